// Round 10
// baseline (158.289 us; speedup 1.0000x reference)
//
#include <hip/hip_runtime.h>
#include <math.h>

#define NPTS 512
#define CH   128
#define NB   2
#define KVAL 460   // int(512 * (1 - 0.1))

typedef __attribute__((ext_vector_type(8))) short short8;
typedef __attribute__((ext_vector_type(4))) float f32x4;

union S8U { short8 s8; unsigned u[4]; uint4 u4; };

__device__ __forceinline__ unsigned short f2bf_rne(float f) {
    unsigned int u = __float_as_uint(f);
    u += 0x7fffu + ((u >> 16) & 1u);
    return (unsigned short)(u >> 16);
}
__device__ __forceinline__ unsigned pk_rne(float a, float b) {
    return ((unsigned)f2bf_rne(a)) | (((unsigned)f2bf_rne(b)) << 16);
}
// pack by truncation: one v_perm_b32 (d^2 values feeding MFMA only)
__device__ __forceinline__ unsigned pk_trunc(float a, float b) {
    return __builtin_amdgcn_perm(__float_as_uint(b), __float_as_uint(a), 0x07060302u);
}

// ===== Kernel A: self-contained TRI mlp =====
// Block = 8i x 32j sub-tile of an upper supertile (ti<=tj); grid 1088.
// W1 frags packed in-kernel (R6-proven, ~+1us); W2 frags packed per-chunk from
// raw global W2 (transient regs, latency hidden before the barrier — R8's
// streaming slot). Persistent regs ~148 -> 3 waves/SIMD. j-width 32 = full
// 128B store lines (R3). fp32 LDS vp (R2/R5). No prep dispatch needed.
__global__ __launch_bounds__(256, 3)
void mlp_tri_kernel(const float* __restrict__ vp,
                    const float* __restrict__ W1,
                    const float* __restrict__ g1, const float* __restrict__ be1,
                    const float* __restrict__ m1, const float* __restrict__ v1,
                    const float* __restrict__ W2,
                    const float* __restrict__ g2, const float* __restrict__ be2,
                    const float* __restrict__ m2, const float* __restrict__ v2,
                    const float* __restrict__ W3, const float* __restrict__ b3,
                    float* __restrict__ ns_out, float* __restrict__ sg_out)
{
    __shared__ __align__(16) float    sVI[8*132];    //  4,224 B
    __shared__ __align__(16) float    sVJ[32*132];   // 16,896 B
    __shared__ __align__(16) unsigned sH1[64*68];    // 17,408 B (bf16x2)
    __shared__ float sPart[2][64];                   //    512 B  -> 39.0 KB

    const int t    = threadIdx.x;
    const int lane = t & 63;
    const int w    = t >> 6;
    const int h    = w & 1;
    const int g    = w >> 1;
    const int l15  = lane & 15;
    const int q    = lane >> 4;
    const int q8   = q * 8;
    const int b    = blockIdx.y;

    int x = blockIdx.x;              // [0, 544)
    const int sub = x & 3;
    int s = x >> 2;                  // [0,136) upper-tri supertile
    int ti = 0;
    while (s >= 16 - ti) { s -= 16 - ti; ++ti; }
    const int i0 = ti*32 + sub*8;
    const int j0 = (ti + s)*32;

    // ---- stage vp tiles in fp32 (coalesced float4) ----
    {
        int r = t >> 5, c4 = (t & 31) * 4;
        *(float4*)&sVI[r*132 + c4] = *(const float4*)&vp[((size_t)(b*NPTS + i0 + r))*CH + c4];
    }
    for (int k = 0; k < 4; ++k) {
        int idx = k*256 + t;
        int r = idx >> 5, c4 = (idx & 31) * 4;
        *(float4*)&sVJ[r*132 + c4] = *(const float4*)&vp[((size_t)(b*NPTS + j0 + r))*CH + c4];
    }

    // ---- in-kernel W1 pack (BN1 scale folded) + BN constants ----
    short8 w1f[4][4];
    float  t1v[4], sc2v[2], t2v[2], w3v[2];
    #pragma unroll
    for (int nt = 0; nt < 4; ++nt) {
        int o = g*64 + nt*16 + l15;
        float sc = g1[o] * rsqrtf(v1[o] + 1e-5f);
        t1v[nt] = be1[o] - m1[o]*sc;
        #pragma unroll
        for (int kt = 0; kt < 4; ++kt) {
            const float* p = &W1[(size_t)o*CH + kt*32 + q8];
            float4 x0 = *(const float4*)p;
            float4 x1 = *(const float4*)(p + 4);
            S8U u;
            u.u[0] = pk_rne(x0.x*sc, x0.y*sc);
            u.u[1] = pk_rne(x0.z*sc, x0.w*sc);
            u.u[2] = pk_rne(x1.x*sc, x1.y*sc);
            u.u[3] = pk_rne(x1.z*sc, x1.w*sc);
            w1f[nt][kt] = u.s8;
        }
    }
    #pragma unroll
    for (int nt = 0; nt < 2; ++nt) {
        int o = g*32 + nt*16 + l15;
        float sc = g2[o] * rsqrtf(v2[o] + 1e-5f);
        sc2v[nt] = sc;
        t2v[nt] = be2[o] - m2[o]*sc;
        w3v[nt] = W3[o];
    }
    const float b3v = b3[0];
    __syncthreads();

    // ---- 4 chunks of 2 i-rows x 32 j = 64 pairs ----
    #pragma unroll 1
    for (int ch = 0; ch < 4; ++ch) {
        const int iirow = ch*2 + h;

        // ===== layer 1: fp32 A-build in MFMA layout; ns free in fp32 =====
        #pragma unroll
        for (int ms = 0; ms < 2; ++ms) {
            short8 afr[4];
            float ns = 0.f;
            #pragma unroll
            for (int kt = 0; kt < 4; ++kt) {
                const float* vi = &sVI[iirow*132 + kt*32 + q8];           // broadcast
                const float* vj = &sVJ[(ms*16 + l15)*132 + kt*32 + q8];   // per-lane
                float4 a0 = *(const float4*)vi, a1 = *(const float4*)(vi + 4);
                float4 c0 = *(const float4*)vj, c1 = *(const float4*)(vj + 4);
                float d0 = a0.x - c0.x, d1 = a0.y - c0.y, d2 = a0.z - c0.z, d3 = a0.w - c0.w;
                float d4 = a1.x - c1.x, d5 = a1.y - c1.y, d6 = a1.z - c1.z, d7 = a1.w - c1.w;
                float p0 = d0*d0, p1 = d1*d1, p2 = d2*d2, p3 = d3*d3;
                float p4 = d4*d4, p5 = d5*d5, p6 = d6*d6, p7 = d7*d7;
                ns += ((p0 + p1) + (p2 + p3)) + ((p4 + p5) + (p6 + p7));
                S8U u;
                u.u[0] = pk_trunc(p0, p1);
                u.u[1] = pk_trunc(p2, p3);
                u.u[2] = pk_trunc(p4, p5);
                u.u[3] = pk_trunc(p6, p7);
                afr[kt] = u.s8;
            }
            ns += __shfl_xor(ns, 16);
            ns += __shfl_xor(ns, 32);
            if (g == 0 && lane < 16) {
                ns_out[((size_t)(b*NPTS + i0 + iirow))*NPTS + j0 + ms*16 + lane] = -ns;
            }

            #pragma unroll
            for (int nt = 0; nt < 4; ++nt) {
                f32x4 acc = {0.f, 0.f, 0.f, 0.f};
                acc = __builtin_amdgcn_mfma_f32_16x16x32_bf16(afr[0], w1f[nt][0], acc, 0, 0, 0);
                acc = __builtin_amdgcn_mfma_f32_16x16x32_bf16(afr[1], w1f[nt][1], acc, 0, 0, 0);
                acc = __builtin_amdgcn_mfma_f32_16x16x32_bf16(afr[2], w1f[nt][2], acc, 0, 0, 0);
                acc = __builtin_amdgcn_mfma_f32_16x16x32_bf16(afr[3], w1f[nt][3], acc, 0, 0, 0);
                float hv0 = acc[0] + t1v[nt]; hv0 = hv0 > 0.f ? hv0 : hv0*0.01f;
                float hv1 = acc[1] + t1v[nt]; hv1 = hv1 > 0.f ? hv1 : hv1*0.01f;
                float hv2 = acc[2] + t1v[nt]; hv2 = hv2 > 0.f ? hv2 : hv2*0.01f;
                float hv3 = acc[3] + t1v[nt]; hv3 = hv3 > 0.f ? hv3 : hv3*0.01f;
                float ov0 = __shfl_xor(hv0, 1);
                float ov1 = __shfl_xor(hv1, 1);
                float ov2 = __shfl_xor(hv2, 1);
                float ov3 = __shfl_xor(hv3, 1);
                bool odd = (l15 & 1);
                float lo0 = odd ? ov2 : hv0,  hi0 = odd ? hv2 : ov0;
                float lo1 = odd ? ov3 : hv1,  hi1 = odd ? hv3 : ov1;
                unsigned w0 = pk_trunc(lo0, hi0);
                unsigned w1 = pk_trunc(lo1, hi1);
                int col = g*32 + nt*8 + (l15 >> 1);
                int row = h*32 + ms*16 + q*4 + (odd ? 2 : 0);
                sH1[row*68 + col]     = w0;
                sH1[(row+1)*68 + col] = w1;
            }
        }
        // per-chunk W2 frag pack from raw global (transient; L1/L2-resident
        // 32 KB W2; latency hidden by the barrier wait — R8's streaming slot)
        S8U wf[8];
        #pragma unroll
        for (int nt = 0; nt < 2; ++nt)
            #pragma unroll
            for (int kt = 0; kt < 4; ++kt) {
                const float* p = &W2[(size_t)(g*32 + nt*16 + l15)*CH + kt*32 + q8];
                float4 x0 = *(const float4*)p;
                float4 x1 = *(const float4*)(p + 4);
                float sc = sc2v[nt];
                S8U u;
                u.u[0] = pk_rne(x0.x*sc, x0.y*sc);
                u.u[1] = pk_rne(x0.z*sc, x0.w*sc);
                u.u[2] = pk_rne(x1.x*sc, x1.y*sc);
                u.u[3] = pk_rne(x1.z*sc, x1.w*sc);
                wf[nt*4 + kt] = u;
            }
        __syncthreads();

        // ===== layer 2 (+BN fold) + layer 3 dot =====
        #pragma unroll
        for (int sidx = 0; sidx < 2; ++sidx) {
            short8 hfr[4];
            #pragma unroll
            for (int kt = 0; kt < 4; ++kt)
                hfr[kt] = *(const short8*)&sH1[(h*32 + sidx*16 + l15)*68 + kt*16 + q*4];

            float part[4] = {0.f, 0.f, 0.f, 0.f};
            #pragma unroll
            for (int nt = 0; nt < 2; ++nt) {
                f32x4 acc = {0.f, 0.f, 0.f, 0.f};
                acc = __builtin_amdgcn_mfma_f32_16x16x32_bf16(hfr[0], wf[nt*4+0].s8, acc, 0, 0, 0);
                acc = __builtin_amdgcn_mfma_f32_16x16x32_bf16(hfr[1], wf[nt*4+1].s8, acc, 0, 0, 0);
                acc = __builtin_amdgcn_mfma_f32_16x16x32_bf16(hfr[2], wf[nt*4+2].s8, acc, 0, 0, 0);
                acc = __builtin_amdgcn_mfma_f32_16x16x32_bf16(hfr[3], wf[nt*4+3].s8, acc, 0, 0, 0);
                #pragma unroll
                for (int r = 0; r < 4; ++r) {
                    float hv = acc[r] + t2v[nt];
                    hv = hv > 0.f ? hv : hv*0.01f;
                    part[r] = fmaf(hv, w3v[nt], part[r]);
                }
            }
            #pragma unroll
            for (int r = 0; r < 4; ++r) {
                part[r] += __shfl_xor(part[r], 1);
                part[r] += __shfl_xor(part[r], 2);
                part[r] += __shfl_xor(part[r], 4);
                part[r] += __shfl_xor(part[r], 8);
            }
            if (l15 == 0) {
                #pragma unroll
                for (int r = 0; r < 4; ++r)
                    sPart[g][h*32 + sidx*16 + q*4 + r] = part[r];
            }
        }
        __syncthreads();

        // ===== epilogue: raw sigmoid (finish applies ep_last) =====
        if (t < 64) {
            float logit = sPart[0][t] + sPart[1][t] + b3v;
            float sg = 1.f / (1.f + __expf(-logit));
            int i = i0 + ch*2 + (t >> 5);
            int j = j0 + (t & 31);
            sg_out[((size_t)(b*NPTS + i))*NPTS + j] = sg;   // full 128B lines
        }
    }
}

// ---- reductions ----
__device__ __forceinline__ float block_reduce_sum512(float v, float* red) {
    #pragma unroll
    for (int off = 32; off; off >>= 1) v += __shfl_down(v, off);
    int wid = threadIdx.x >> 6;
    if ((threadIdx.x & 63) == 0) red[wid] = v;
    __syncthreads();
    float s = ((red[0] + red[1]) + (red[2] + red[3]))
            + ((red[4] + red[5]) + (red[6] + red[7]));
    __syncthreads();
    return s;
}

// ===== Kernel B: fused mirror-gather + topk + L1 renorm + diag + row norm =====
// R7-proven: lower-region elements are gathered from the upper triangle written
// by kernel A; finish writes only its own row (ep full, ns lower) -> race-free.
__global__ __launch_bounds__(512)
void finish_kernel(const float* __restrict__ ep_gen, const float* __restrict__ sg_buf,
                   float* __restrict__ ep_out, float* __restrict__ ns_out)
{
    __shared__ __align__(16) float r[NPTS];
    __shared__ float red[8];
    const int row = blockIdx.x;          // b*512 + i
    const int b   = row >> 9;
    const int i   = row & (NPTS - 1);
    const int ti  = i >> 5;
    const int t   = threadIdx.x;         // = j

    const bool lower = (t >> 5) < ti;    // supertile(j) < supertile(i): mirror
    float sg;
    if (lower) {
        sg = sg_buf[((size_t)(b*NPTS + t))*NPTS + i];                  // gather [j][i]
        ns_out[(size_t)row*NPTS + t] = ns_out[((size_t)(b*NPTS + t))*NPTS + i];
    } else {
        sg = sg_buf[(size_t)row*NPTS + t];                             // row read
    }
    float gv = (t == i) ? 0.f : ep_gen[(size_t)row*NPTS + t];
    float v = sg * gv;
    r[t] = v;
    __syncthreads();

    float s_last = block_reduce_sum512(gv, red);

    // rank by strict-greater count; sigmoid*uniform values: exact float ties
    // are measure-zero, index tiebreak cannot change the kept set.
    int c = 0;
    #pragma unroll 4
    for (int k = 0; k < NPTS; k += 4) {
        float4 rv = *(const float4*)&r[k];
        c += (rv.x > v) + (rv.y > v) + (rv.z > v) + (rv.w > v);
    }
    float m = (c < KVAL) ? v : 0.f;

    float l1 = block_reduce_sum512(m, red);
    float scale = s_last / fmaxf(l1, 1e-12f);
    float f = m*scale + ((t == i) ? 1.f : 0.f) + 1e-6f;

    float s2 = block_reduce_sum512(f, red);
    ep_out[(size_t)row*NPTS + t] = f / s2;
}

// ================= fallback path (ws too small): R8-proven ==================
__global__ __launch_bounds__(256, 3)
void mlp_full_kernel(const float* __restrict__ vp, const float* __restrict__ ep,
                     const float* __restrict__ W1,
                     const float* __restrict__ g1, const float* __restrict__ be1,
                     const float* __restrict__ m1, const float* __restrict__ v1,
                     const float* __restrict__ W2,
                     const float* __restrict__ g2, const float* __restrict__ be2,
                     const float* __restrict__ m2, const float* __restrict__ v2,
                     const float* __restrict__ W3, const float* __restrict__ b3,
                     float* __restrict__ ep_out, float* __restrict__ ns_out)
{
    __shared__ __align__(16) float    sVI[8*132];
    __shared__ __align__(16) float    sVJ[32*132];
    __shared__ __align__(16) unsigned sH1[64*68];
    __shared__ float sPart[2][64];

    const int t    = threadIdx.x;
    const int lane = t & 63;
    const int w    = t >> 6;
    const int h    = w & 1;
    const int g    = w >> 1;
    const int l15  = lane & 15;
    const int q    = lane >> 4;
    const int q8   = q * 8;
    const int b    = blockIdx.y;
    const int i0   = (blockIdx.x >> 4) * 8;
    const int j0   = (blockIdx.x & 15) * 32;

    {
        int r = t >> 5, c4 = (t & 31) * 4;
        *(float4*)&sVI[r*132 + c4] = *(const float4*)&vp[((size_t)(b*NPTS + i0 + r))*CH + c4];
    }
    for (int k = 0; k < 4; ++k) {
        int idx = k*256 + t;
        int r = idx >> 5, c4 = (idx & 31) * 4;
        *(float4*)&sVJ[r*132 + c4] = *(const float4*)&vp[((size_t)(b*NPTS + j0 + r))*CH + c4];
    }
    short8 w1f[4][4]; float t1v[4];
    short8 w2f[2][4]; float t2v[2], w3v[2];
    #pragma unroll
    for (int nt = 0; nt < 4; ++nt) {
        int o = g*64 + nt*16 + l15;
        float sc = g1[o] * rsqrtf(v1[o] + 1e-5f);
        t1v[nt] = be1[o] - m1[o]*sc;
        #pragma unroll
        for (int kt = 0; kt < 4; ++kt) {
            const float* p = &W1[(size_t)o*CH + kt*32 + q8];
            float4 x0 = *(const float4*)p;
            float4 x1 = *(const float4*)(p + 4);
            S8U u;
            u.u[0] = pk_rne(x0.x*sc, x0.y*sc);
            u.u[1] = pk_rne(x0.z*sc, x0.w*sc);
            u.u[2] = pk_rne(x1.x*sc, x1.y*sc);
            u.u[3] = pk_rne(x1.z*sc, x1.w*sc);
            w1f[nt][kt] = u.s8;
        }
    }
    #pragma unroll
    for (int nt = 0; nt < 2; ++nt) {
        int o = g*32 + nt*16 + l15;
        float sc = g2[o] * rsqrtf(v2[o] + 1e-5f);
        t2v[nt] = be2[o] - m2[o]*sc;
        w3v[nt] = W3[o];
        #pragma unroll
        for (int kt = 0; kt < 4; ++kt) {
            const float* p = &W2[(size_t)o*CH + kt*32 + q8];
            float4 x0 = *(const float4*)p;
            float4 x1 = *(const float4*)(p + 4);
            S8U u;
            u.u[0] = pk_rne(x0.x*sc, x0.y*sc);
            u.u[1] = pk_rne(x0.z*sc, x0.w*sc);
            u.u[2] = pk_rne(x1.x*sc, x1.y*sc);
            u.u[3] = pk_rne(x1.z*sc, x1.w*sc);
            w2f[nt][kt] = u.s8;
        }
    }
    const float b3v = b3[0];
    __syncthreads();

    #pragma unroll 1
    for (int ch = 0; ch < 4; ++ch) {
        const int iirow = ch*2 + h;
        #pragma unroll
        for (int ms = 0; ms < 2; ++ms) {
            short8 afr[4];
            float ns = 0.f;
            #pragma unroll
            for (int kt = 0; kt < 4; ++kt) {
                const float* vi = &sVI[iirow*132 + kt*32 + q8];
                const float* vj = &sVJ[(ms*16 + l15)*132 + kt*32 + q8];
                float4 a0 = *(const float4*)vi, a1 = *(const float4*)(vi + 4);
                float4 c0 = *(const float4*)vj, c1 = *(const float4*)(vj + 4);
                float d0 = a0.x - c0.x, d1 = a0.y - c0.y, d2 = a0.z - c0.z, d3 = a0.w - c0.w;
                float d4 = a1.x - c1.x, d5 = a1.y - c1.y, d6 = a1.z - c1.z, d7 = a1.w - c1.w;
                float p0 = d0*d0, p1 = d1*d1, p2 = d2*d2, p3 = d3*d3;
                float p4 = d4*d4, p5 = d5*d5, p6 = d6*d6, p7 = d7*d7;
                ns += ((p0 + p1) + (p2 + p3)) + ((p4 + p5) + (p6 + p7));
                S8U u;
                u.u[0] = pk_trunc(p0, p1);
                u.u[1] = pk_trunc(p2, p3);
                u.u[2] = pk_trunc(p4, p5);
                u.u[3] = pk_trunc(p6, p7);
                afr[kt] = u.s8;
            }
            ns += __shfl_xor(ns, 16);
            ns += __shfl_xor(ns, 32);
            if (g == 0 && lane < 16)
                ns_out[((size_t)(b*NPTS + i0 + iirow))*NPTS + j0 + ms*16 + lane] = -ns;
            #pragma unroll
            for (int nt = 0; nt < 4; ++nt) {
                f32x4 acc = {0.f, 0.f, 0.f, 0.f};
                acc = __builtin_amdgcn_mfma_f32_16x16x32_bf16(afr[0], w1f[nt][0], acc, 0, 0, 0);
                acc = __builtin_amdgcn_mfma_f32_16x16x32_bf16(afr[1], w1f[nt][1], acc, 0, 0, 0);
                acc = __builtin_amdgcn_mfma_f32_16x16x32_bf16(afr[2], w1f[nt][2], acc, 0, 0, 0);
                acc = __builtin_amdgcn_mfma_f32_16x16x32_bf16(afr[3], w1f[nt][3], acc, 0, 0, 0);
                float hv0 = acc[0] + t1v[nt]; hv0 = hv0 > 0.f ? hv0 : hv0*0.01f;
                float hv1 = acc[1] + t1v[nt]; hv1 = hv1 > 0.f ? hv1 : hv1*0.01f;
                float hv2 = acc[2] + t1v[nt]; hv2 = hv2 > 0.f ? hv2 : hv2*0.01f;
                float hv3 = acc[3] + t1v[nt]; hv3 = hv3 > 0.f ? hv3 : hv3*0.01f;
                float ov0 = __shfl_xor(hv0, 1);
                float ov1 = __shfl_xor(hv1, 1);
                float ov2 = __shfl_xor(hv2, 1);
                float ov3 = __shfl_xor(hv3, 1);
                bool odd = (l15 & 1);
                float lo0 = odd ? ov2 : hv0,  hi0 = odd ? hv2 : ov0;
                float lo1 = odd ? ov3 : hv1,  hi1 = odd ? hv3 : ov1;
                int col = g*32 + nt*8 + (l15 >> 1);
                int row = h*32 + ms*16 + q*4 + (odd ? 2 : 0);
                sH1[row*68 + col]     = pk_trunc(lo0, hi0);
                sH1[(row+1)*68 + col] = pk_trunc(lo1, hi1);
            }
        }
        __syncthreads();
        #pragma unroll
        for (int sx = 0; sx < 2; ++sx) {
            short8 hfr[4];
            #pragma unroll
            for (int kt = 0; kt < 4; ++kt)
                hfr[kt] = *(const short8*)&sH1[(h*32 + sx*16 + l15)*68 + kt*16 + q*4];
            float part[4] = {0.f, 0.f, 0.f, 0.f};
            #pragma unroll
            for (int nt = 0; nt < 2; ++nt) {
                f32x4 acc = {0.f, 0.f, 0.f, 0.f};
                acc = __builtin_amdgcn_mfma_f32_16x16x32_bf16(hfr[0], w2f[nt][0], acc, 0, 0, 0);
                acc = __builtin_amdgcn_mfma_f32_16x16x32_bf16(hfr[1], w2f[nt][1], acc, 0, 0, 0);
                acc = __builtin_amdgcn_mfma_f32_16x16x32_bf16(hfr[2], w2f[nt][2], acc, 0, 0, 0);
                acc = __builtin_amdgcn_mfma_f32_16x16x32_bf16(hfr[3], w2f[nt][3], acc, 0, 0, 0);
                #pragma unroll
                for (int r = 0; r < 4; ++r) {
                    float hv = acc[r] + t2v[nt];
                    hv = hv > 0.f ? hv : hv*0.01f;
                    part[r] = fmaf(hv, w3v[nt], part[r]);
                }
            }
            #pragma unroll
            for (int r = 0; r < 4; ++r) {
                part[r] += __shfl_xor(part[r], 1);
                part[r] += __shfl_xor(part[r], 2);
                part[r] += __shfl_xor(part[r], 4);
                part[r] += __shfl_xor(part[r], 8);
            }
            if (l15 == 0)
                #pragma unroll
                for (int r = 0; r < 4; ++r)
                    sPart[g][h*32 + sx*16 + q*4 + r] = part[r];
        }
        __syncthreads();
        if (t < 64) {
            float logit = sPart[0][t] + sPart[1][t] + b3v;
            float sg = 1.f / (1.f + __expf(-logit));
            int i = i0 + ch*2 + (t >> 5);
            int j = j0 + (t & 31);
            float epl = (i == j) ? 0.f : ep[((size_t)(b*NPTS + i))*NPTS + j];
            ep_out[((size_t)(b*NPTS + i))*NPTS + j] = sg * epl;
        }
    }
}

__global__ __launch_bounds__(512)
void topk_norm_kernel(const float* __restrict__ ep_gen, float* __restrict__ ep_io) {
    __shared__ __align__(16) float r[NPTS];
    __shared__ float red[8];
    const int row = blockIdx.x;
    const int i   = row & (NPTS - 1);
    const int t   = threadIdx.x;
    const float* gen = &ep_gen[(size_t)row * NPTS];
    float* io        = &ep_io [(size_t)row * NPTS];
    float v = io[t];
    r[t] = v;
    float gv = (t == i) ? 0.f : gen[t];
    __syncthreads();
    float s_last = block_reduce_sum512(gv, red);
    int c = 0;
    #pragma unroll 4
    for (int k = 0; k < NPTS; k += 4) {
        float4 rv = *(const float4*)&r[k];
        c += (rv.x > v) + (rv.y > v) + (rv.z > v) + (rv.w > v);
    }
    float m = (c < KVAL) ? v : 0.f;
    float l1 = block_reduce_sum512(m, red);
    float scale = s_last / fmaxf(l1, 1e-12f);
    float f = m*scale + ((t == i) ? 1.f : 0.f) + 1e-6f;
    float s2 = block_reduce_sum512(f, red);
    io[t] = f / s2;
}

extern "C" void kernel_launch(void* const* d_in, const int* in_sizes, int n_in,
                              void* d_out, int out_size, void* d_ws, size_t ws_size,
                              hipStream_t stream) {
    const float* vp  = (const float*)d_in[0];
    const float* ep  = (const float*)d_in[1];
    const float* W1  = (const float*)d_in[2];
    const float* g1  = (const float*)d_in[3];
    const float* be1 = (const float*)d_in[4];
    const float* m1  = (const float*)d_in[5];
    const float* v1  = (const float*)d_in[6];
    const float* W2  = (const float*)d_in[7];
    const float* g2  = (const float*)d_in[8];
    const float* be2 = (const float*)d_in[9];
    const float* m2  = (const float*)d_in[10];
    const float* v2  = (const float*)d_in[11];
    const float* W3  = (const float*)d_in[12];
    const float* b3  = (const float*)d_in[13];

    float* out    = (float*)d_out;
    float* ep_out = out;                          // [2,512,512]
    float* ns_out = out + (size_t)NB*NPTS*NPTS;   // [2,512,512]

    const size_t need = (size_t)NB*NPTS*NPTS*sizeof(float);   // 2 MB sg_buf
    if (ws_size >= need) {
        float* sg_buf = (float*)d_ws;
        mlp_tri_kernel<<<dim3(544, NB), dim3(256), 0, stream>>>(
            vp, W1, g1, be1, m1, v1, W2, g2, be2, m2, v2, W3, b3, ns_out, sg_buf);
        finish_kernel<<<dim3(NB*NPTS), dim3(512), 0, stream>>>(ep, sg_buf, ep_out, ns_out);
    } else {
        mlp_full_kernel<<<dim3(1024, NB), dim3(256), 0, stream>>>(
            vp, ep, W1, g1, be1, m1, v1, W2, g2, be2, m2, v2, W3, b3, ep_out, ns_out);
        topk_norm_kernel<<<dim3(NB*NPTS), dim3(512), 0, stream>>>(ep, ep_out);
    }
}

// Round 11
// 143.005 us; speedup vs baseline: 1.1069x; 1.1069x over previous
//
#include <hip/hip_runtime.h>
#include <math.h>

#define NPTS 512
#define CH   128
#define NB   2
#define KVAL 460   // int(512 * (1 - 0.1))

typedef __attribute__((ext_vector_type(8))) short short8;
typedef __attribute__((ext_vector_type(4))) float f32x4;

union S8U { short8 s8; unsigned u[4]; uint4 u4; };

__device__ __forceinline__ unsigned short f2bf_rne(float f) {
    unsigned int u = __float_as_uint(f);
    u += 0x7fffu + ((u >> 16) & 1u);
    return (unsigned short)(u >> 16);
}
__device__ __forceinline__ unsigned pk_rne(float a, float b) {
    return ((unsigned)f2bf_rne(a)) | (((unsigned)f2bf_rne(b)) << 16);
}
// pack by truncation: one v_perm_b32 (d^2 values feeding MFMA only)
__device__ __forceinline__ unsigned pk_trunc(float a, float b) {
    return __builtin_amdgcn_perm(__float_as_uint(b), __float_as_uint(a), 0x07060302u);
}

// ---- prep: BN-folded bf16 weight B-fragments, fragment-ordered in ws ----
// R8-proven. Worth ~20us vs in-kernel packing (R10 measured 64 vs 43).
__global__ __launch_bounds__(256)
void prep_weights(const float* __restrict__ W1, const float* __restrict__ g1,
                  const float* __restrict__ v1,
                  const float* __restrict__ W2, const float* __restrict__ g2,
                  const float* __restrict__ v2, uint4* __restrict__ wsp)
{
    int e = blockIdx.x * 256 + threadIdx.x;   // [0, 3072)
    if (e < 2048) {
        int idx = e >> 6, lane = e & 63;
        int g = idx >> 4, nt = (idx >> 2) & 3, kt = idx & 3;
        int o = g*64 + nt*16 + (lane & 15);
        int kb = kt*32 + (lane >> 4)*8;
        float s = g1[o] * rsqrtf(v1[o] + 1e-5f);
        const float* p = &W1[(size_t)o*CH + kb];
        uint4 v;
        v.x = pk_rne(p[0]*s, p[1]*s);
        v.y = pk_rne(p[2]*s, p[3]*s);
        v.z = pk_rne(p[4]*s, p[5]*s);
        v.w = pk_rne(p[6]*s, p[7]*s);
        wsp[e] = v;
    } else if (e < 3072) {
        int e2 = e - 2048;
        int idx = e2 >> 6, lane = e2 & 63;
        int g = idx >> 3, nt = (idx >> 2) & 1, kt = idx & 3;
        int o = g*32 + nt*16 + (lane & 15);
        int kb = kt*32 + (lane >> 4)*8;
        float s = g2[o] * rsqrtf(v2[o] + 1e-5f);
        const float* p = &W2[(size_t)o*CH + kb];
        uint4 v;
        v.x = pk_rne(p[0]*s, p[1]*s);
        v.y = pk_rne(p[2]*s, p[3]*s);
        v.z = pk_rne(p[4]*s, p[5]*s);
        v.w = pk_rne(p[6]*s, p[7]*s);
        wsp[e] = v;
    }
}

// ===== TRI mlp: exactly R8's best-measured kernel (43.0 us) =====
// Block = 8i x 32j sub-tile of an upper supertile (ti<=tj); grid 1088.
// w1f one-time from wsp; W2 frags streamed per-chunk from wsp (transient).
// j-width 32 = full 128B store lines (R3). fp32 LDS vp (R2/R5).
__global__ __launch_bounds__(256, 3)
void mlp_tri_kernel(const float* __restrict__ vp, const uint4* __restrict__ wsp,
                    const float* __restrict__ g1, const float* __restrict__ be1,
                    const float* __restrict__ m1, const float* __restrict__ v1,
                    const float* __restrict__ g2, const float* __restrict__ be2,
                    const float* __restrict__ m2, const float* __restrict__ v2,
                    const float* __restrict__ W3, const float* __restrict__ b3,
                    float* __restrict__ ns_out, float* __restrict__ sg_out)
{
    __shared__ __align__(16) float    sVI[8*132];    //  4,224 B
    __shared__ __align__(16) float    sVJ[32*132];   // 16,896 B
    __shared__ __align__(16) unsigned sH1[64*68];    // 17,408 B (bf16x2)
    __shared__ float sPart[2][64];                   //    512 B  -> 39.0 KB

    const int t    = threadIdx.x;
    const int lane = t & 63;
    const int w    = t >> 6;
    const int h    = w & 1;
    const int g    = w >> 1;
    const int l15  = lane & 15;
    const int q    = lane >> 4;
    const int q8   = q * 8;
    const int b    = blockIdx.y;

    int x = blockIdx.x;              // [0, 544)
    const int sub = x & 3;
    int s = x >> 2;                  // [0,136) upper-tri supertile
    int ti = 0;
    while (s >= 16 - ti) { s -= 16 - ti; ++ti; }
    const int i0 = ti*32 + sub*8;
    const int j0 = (ti + s)*32;

    // ---- stage vp tiles in fp32 (coalesced float4) ----
    {
        int r = t >> 5, c4 = (t & 31) * 4;
        *(float4*)&sVI[r*132 + c4] = *(const float4*)&vp[((size_t)(b*NPTS + i0 + r))*CH + c4];
    }
    for (int k = 0; k < 4; ++k) {
        int idx = k*256 + t;
        int r = idx >> 5, c4 = (idx & 31) * 4;
        *(float4*)&sVJ[r*132 + c4] = *(const float4*)&vp[((size_t)(b*NPTS + j0 + r))*CH + c4];
    }

    // ---- w1f: one-time coalesced load of prep-packed fragments ----
    short8 w1f[4][4];
    #pragma unroll
    for (int nt = 0; nt < 4; ++nt)
        #pragma unroll
        for (int kt = 0; kt < 4; ++kt) {
            S8U u; u.u4 = wsp[((g*4 + nt)*4 + kt)*64 + lane];
            w1f[nt][kt] = u.s8;
        }

    // ---- BN shifts / W3 (per-lane) ----
    float t1v[4], t2v[2], w3v[2];
    #pragma unroll
    for (int nt = 0; nt < 4; ++nt) {
        int o = g*64 + nt*16 + l15;
        float sc = g1[o] * rsqrtf(v1[o] + 1e-5f);
        t1v[nt] = be1[o] - m1[o]*sc;
    }
    #pragma unroll
    for (int nt = 0; nt < 2; ++nt) {
        int o = g*32 + nt*16 + l15;
        float sc = g2[o] * rsqrtf(v2[o] + 1e-5f);
        t2v[nt] = be2[o] - m2[o]*sc;
        w3v[nt] = W3[o];
    }
    const float b3v = b3[0];
    __syncthreads();

    // ---- 4 chunks of 2 i-rows x 32 j = 64 pairs ----
    #pragma unroll 1
    for (int ch = 0; ch < 4; ++ch) {
        const int iirow = ch*2 + h;

        // ===== layer 1: fp32 A-build in MFMA layout; ns free in fp32 =====
        #pragma unroll
        for (int ms = 0; ms < 2; ++ms) {
            short8 afr[4];
            float ns = 0.f;
            #pragma unroll
            for (int kt = 0; kt < 4; ++kt) {
                const float* vi = &sVI[iirow*132 + kt*32 + q8];           // broadcast
                const float* vj = &sVJ[(ms*16 + l15)*132 + kt*32 + q8];   // per-lane
                float4 a0 = *(const float4*)vi, a1 = *(const float4*)(vi + 4);
                float4 c0 = *(const float4*)vj, c1 = *(const float4*)(vj + 4);
                float d0 = a0.x - c0.x, d1 = a0.y - c0.y, d2 = a0.z - c0.z, d3 = a0.w - c0.w;
                float d4 = a1.x - c1.x, d5 = a1.y - c1.y, d6 = a1.z - c1.z, d7 = a1.w - c1.w;
                float p0 = d0*d0, p1 = d1*d1, p2 = d2*d2, p3 = d3*d3;
                float p4 = d4*d4, p5 = d5*d5, p6 = d6*d6, p7 = d7*d7;
                ns += ((p0 + p1) + (p2 + p3)) + ((p4 + p5) + (p6 + p7));
                S8U u;
                u.u[0] = pk_trunc(p0, p1);
                u.u[1] = pk_trunc(p2, p3);
                u.u[2] = pk_trunc(p4, p5);
                u.u[3] = pk_trunc(p6, p7);
                afr[kt] = u.s8;
            }
            ns += __shfl_xor(ns, 16);
            ns += __shfl_xor(ns, 32);
            if (g == 0 && lane < 16) {
                ns_out[((size_t)(b*NPTS + i0 + iirow))*NPTS + j0 + ms*16 + lane] = -ns;
            }

            #pragma unroll
            for (int nt = 0; nt < 4; ++nt) {
                f32x4 acc = {0.f, 0.f, 0.f, 0.f};
                acc = __builtin_amdgcn_mfma_f32_16x16x32_bf16(afr[0], w1f[nt][0], acc, 0, 0, 0);
                acc = __builtin_amdgcn_mfma_f32_16x16x32_bf16(afr[1], w1f[nt][1], acc, 0, 0, 0);
                acc = __builtin_amdgcn_mfma_f32_16x16x32_bf16(afr[2], w1f[nt][2], acc, 0, 0, 0);
                acc = __builtin_amdgcn_mfma_f32_16x16x32_bf16(afr[3], w1f[nt][3], acc, 0, 0, 0);
                float hv0 = acc[0] + t1v[nt]; hv0 = hv0 > 0.f ? hv0 : hv0*0.01f;
                float hv1 = acc[1] + t1v[nt]; hv1 = hv1 > 0.f ? hv1 : hv1*0.01f;
                float hv2 = acc[2] + t1v[nt]; hv2 = hv2 > 0.f ? hv2 : hv2*0.01f;
                float hv3 = acc[3] + t1v[nt]; hv3 = hv3 > 0.f ? hv3 : hv3*0.01f;
                float ov0 = __shfl_xor(hv0, 1);
                float ov1 = __shfl_xor(hv1, 1);
                float ov2 = __shfl_xor(hv2, 1);
                float ov3 = __shfl_xor(hv3, 1);
                bool odd = (l15 & 1);
                float lo0 = odd ? ov2 : hv0,  hi0 = odd ? hv2 : ov0;
                float lo1 = odd ? ov3 : hv1,  hi1 = odd ? hv3 : ov1;
                unsigned w0 = pk_trunc(lo0, hi0);
                unsigned w1 = pk_trunc(lo1, hi1);
                int col = g*32 + nt*8 + (l15 >> 1);
                int row = h*32 + ms*16 + q*4 + (odd ? 2 : 0);
                sH1[row*68 + col]     = w0;
                sH1[(row+1)*68 + col] = w1;
            }
        }
        // stream W2 frags (transient; latency hidden by barrier wait)
        S8U wf[8];
        #pragma unroll
        for (int e = 0; e < 8; ++e)
            wf[e].u4 = wsp[2048 + (g*8 + e)*64 + lane];
        __syncthreads();

        // ===== layer 2 (+BN fold) + layer 3 dot =====
        #pragma unroll
        for (int sidx = 0; sidx < 2; ++sidx) {
            short8 hfr[4];
            #pragma unroll
            for (int kt = 0; kt < 4; ++kt)
                hfr[kt] = *(const short8*)&sH1[(h*32 + sidx*16 + l15)*68 + kt*16 + q*4];

            float part[4] = {0.f, 0.f, 0.f, 0.f};
            #pragma unroll
            for (int nt = 0; nt < 2; ++nt) {
                f32x4 acc = {0.f, 0.f, 0.f, 0.f};
                acc = __builtin_amdgcn_mfma_f32_16x16x32_bf16(hfr[0], wf[nt*4+0].s8, acc, 0, 0, 0);
                acc = __builtin_amdgcn_mfma_f32_16x16x32_bf16(hfr[1], wf[nt*4+1].s8, acc, 0, 0, 0);
                acc = __builtin_amdgcn_mfma_f32_16x16x32_bf16(hfr[2], wf[nt*4+2].s8, acc, 0, 0, 0);
                acc = __builtin_amdgcn_mfma_f32_16x16x32_bf16(hfr[3], wf[nt*4+3].s8, acc, 0, 0, 0);
                #pragma unroll
                for (int r = 0; r < 4; ++r) {
                    float hv = acc[r] + t2v[nt];
                    hv = hv > 0.f ? hv : hv*0.01f;
                    part[r] = fmaf(hv, w3v[nt], part[r]);
                }
            }
            #pragma unroll
            for (int r = 0; r < 4; ++r) {
                part[r] += __shfl_xor(part[r], 1);
                part[r] += __shfl_xor(part[r], 2);
                part[r] += __shfl_xor(part[r], 4);
                part[r] += __shfl_xor(part[r], 8);
            }
            if (l15 == 0) {
                #pragma unroll
                for (int r = 0; r < 4; ++r)
                    sPart[g][h*32 + sidx*16 + q*4 + r] = part[r];
            }
        }
        __syncthreads();

        // ===== epilogue: raw sigmoid (finish applies ep_last) =====
        if (t < 64) {
            float logit = sPart[0][t] + sPart[1][t] + b3v;
            float sg = 1.f / (1.f + __expf(-logit));
            int i = i0 + ch*2 + (t >> 5);
            int j = j0 + (t & 31);
            sg_out[((size_t)(b*NPTS + i))*NPTS + j] = sg;   // full 128B lines
        }
    }
}

// ---- reductions ----
__device__ __forceinline__ float block_reduce_sum512(float v, float* red) {
    #pragma unroll
    for (int off = 32; off; off >>= 1) v += __shfl_down(v, off);
    int wid = threadIdx.x >> 6;
    if ((threadIdx.x & 63) == 0) red[wid] = v;
    __syncthreads();
    float s = ((red[0] + red[1]) + (red[2] + red[3]))
            + ((red[4] + red[5]) + (red[6] + red[7]));
    __syncthreads();
    return s;
}

// ===== finish: R7-proven gather-mirror + topk + L1 renorm + diag + norm =====
// Lower-region elements are gathered from upper-triangle locations written by
// mlp (never written here) -> race-free. Writes own row only (ep full, ns lower).
__global__ __launch_bounds__(512)
void finish_kernel(const float* __restrict__ ep_gen, const float* __restrict__ sg_buf,
                   float* __restrict__ ep_out, float* __restrict__ ns_out)
{
    __shared__ __align__(16) float r[NPTS];
    __shared__ float red[8];
    const int row = blockIdx.x;          // b*512 + i
    const int b   = row >> 9;
    const int i   = row & (NPTS - 1);
    const int ti  = i >> 5;
    const int t   = threadIdx.x;         // = j

    const bool lower = (t >> 5) < ti;    // supertile(j) < supertile(i): mirror
    float sg;
    if (lower) {
        sg = sg_buf[((size_t)(b*NPTS + t))*NPTS + i];                  // gather [j][i]
        ns_out[(size_t)row*NPTS + t] = ns_out[((size_t)(b*NPTS + t))*NPTS + i];
    } else {
        sg = sg_buf[(size_t)row*NPTS + t];                             // row read
    }
    float gv = (t == i) ? 0.f : ep_gen[(size_t)row*NPTS + t];
    float v = sg * gv;
    r[t] = v;
    __syncthreads();

    float s_last = block_reduce_sum512(gv, red);

    // rank by strict-greater count; sigmoid*uniform values: exact float ties
    // are measure-zero, index tiebreak cannot change the kept set.
    int c = 0;
    #pragma unroll 4
    for (int k = 0; k < NPTS; k += 4) {
        float4 rv = *(const float4*)&r[k];
        c += (rv.x > v) + (rv.y > v) + (rv.z > v) + (rv.w > v);
    }
    float m = (c < KVAL) ? v : 0.f;

    float l1 = block_reduce_sum512(m, red);
    float scale = s_last / fmaxf(l1, 1e-12f);
    float f = m*scale + ((t == i) ? 1.f : 0.f) + 1e-6f;

    float s2 = block_reduce_sum512(f, red);
    ep_out[(size_t)row*NPTS + t] = f / s2;
}

// ================= fallback path (ws too small) ==================
__global__ __launch_bounds__(256, 3)
void mlp_full_kernel(const float* __restrict__ vp, const float* __restrict__ ep,
                     const float* __restrict__ W1,
                     const float* __restrict__ g1, const float* __restrict__ be1,
                     const float* __restrict__ m1, const float* __restrict__ v1,
                     const float* __restrict__ W2,
                     const float* __restrict__ g2, const float* __restrict__ be2,
                     const float* __restrict__ m2, const float* __restrict__ v2,
                     const float* __restrict__ W3, const float* __restrict__ b3,
                     float* __restrict__ ep_out, float* __restrict__ ns_out)
{
    __shared__ __align__(16) float    sVI[8*132];
    __shared__ __align__(16) float    sVJ[32*132];
    __shared__ __align__(16) unsigned sH1[64*68];
    __shared__ float sPart[2][64];

    const int t    = threadIdx.x;
    const int lane = t & 63;
    const int w    = t >> 6;
    const int h    = w & 1;
    const int g    = w >> 1;
    const int l15  = lane & 15;
    const int q    = lane >> 4;
    const int q8   = q * 8;
    const int b    = blockIdx.y;
    const int i0   = (blockIdx.x >> 4) * 8;
    const int j0   = (blockIdx.x & 15) * 32;

    {
        int r = t >> 5, c4 = (t & 31) * 4;
        *(float4*)&sVI[r*132 + c4] = *(const float4*)&vp[((size_t)(b*NPTS + i0 + r))*CH + c4];
    }
    for (int k = 0; k < 4; ++k) {
        int idx = k*256 + t;
        int r = idx >> 5, c4 = (idx & 31) * 4;
        *(float4*)&sVJ[r*132 + c4] = *(const float4*)&vp[((size_t)(b*NPTS + j0 + r))*CH + c4];
    }
    short8 w1f[4][4]; float t1v[4];
    short8 w2f[2][4]; float t2v[2], w3v[2];
    #pragma unroll
    for (int nt = 0; nt < 4; ++nt) {
        int o = g*64 + nt*16 + l15;
        float sc = g1[o] * rsqrtf(v1[o] + 1e-5f);
        t1v[nt] = be1[o] - m1[o]*sc;
        #pragma unroll
        for (int kt = 0; kt < 4; ++kt) {
            const float* p = &W1[(size_t)o*CH + kt*32 + q8];
            float4 x0 = *(const float4*)p;
            float4 x1 = *(const float4*)(p + 4);
            S8U u;
            u.u[0] = pk_rne(x0.x*sc, x0.y*sc);
            u.u[1] = pk_rne(x0.z*sc, x0.w*sc);
            u.u[2] = pk_rne(x1.x*sc, x1.y*sc);
            u.u[3] = pk_rne(x1.z*sc, x1.w*sc);
            w1f[nt][kt] = u.s8;
        }
    }
    #pragma unroll
    for (int nt = 0; nt < 2; ++nt) {
        int o = g*32 + nt*16 + l15;
        float sc = g2[o] * rsqrtf(v2[o] + 1e-5f);
        t2v[nt] = be2[o] - m2[o]*sc;
        w3v[nt] = W3[o];
        #pragma unroll
        for (int kt = 0; kt < 4; ++kt) {
            const float* p = &W2[(size_t)o*CH + kt*32 + q8];
            float4 x0 = *(const float4*)p;
            float4 x1 = *(const float4*)(p + 4);
            S8U u;
            u.u[0] = pk_rne(x0.x*sc, x0.y*sc);
            u.u[1] = pk_rne(x0.z*sc, x0.w*sc);
            u.u[2] = pk_rne(x1.x*sc, x1.y*sc);
            u.u[3] = pk_rne(x1.z*sc, x1.w*sc);
            w2f[nt][kt] = u.s8;
        }
    }
    const float b3v = b3[0];
    __syncthreads();

    #pragma unroll 1
    for (int ch = 0; ch < 4; ++ch) {
        const int iirow = ch*2 + h;
        #pragma unroll
        for (int ms = 0; ms < 2; ++ms) {
            short8 afr[4];
            float ns = 0.f;
            #pragma unroll
            for (int kt = 0; kt < 4; ++kt) {
                const float* vi = &sVI[iirow*132 + kt*32 + q8];
                const float* vj = &sVJ[(ms*16 + l15)*132 + kt*32 + q8];
                float4 a0 = *(const float4*)vi, a1 = *(const float4*)(vi + 4);
                float4 c0 = *(const float4*)vj, c1 = *(const float4*)(vj + 4);
                float d0 = a0.x - c0.x, d1 = a0.y - c0.y, d2 = a0.z - c0.z, d3 = a0.w - c0.w;
                float d4 = a1.x - c1.x, d5 = a1.y - c1.y, d6 = a1.z - c1.z, d7 = a1.w - c1.w;
                float p0 = d0*d0, p1 = d1*d1, p2 = d2*d2, p3 = d3*d3;
                float p4 = d4*d4, p5 = d5*d5, p6 = d6*d6, p7 = d7*d7;
                ns += ((p0 + p1) + (p2 + p3)) + ((p4 + p5) + (p6 + p7));
                S8U u;
                u.u[0] = pk_trunc(p0, p1);
                u.u[1] = pk_trunc(p2, p3);
                u.u[2] = pk_trunc(p4, p5);
                u.u[3] = pk_trunc(p6, p7);
                afr[kt] = u.s8;
            }
            ns += __shfl_xor(ns, 16);
            ns += __shfl_xor(ns, 32);
            if (g == 0 && lane < 16)
                ns_out[((size_t)(b*NPTS + i0 + iirow))*NPTS + j0 + ms*16 + lane] = -ns;
            #pragma unroll
            for (int nt = 0; nt < 4; ++nt) {
                f32x4 acc = {0.f, 0.f, 0.f, 0.f};
                acc = __builtin_amdgcn_mfma_f32_16x16x32_bf16(afr[0], w1f[nt][0], acc, 0, 0, 0);
                acc = __builtin_amdgcn_mfma_f32_16x16x32_bf16(afr[1], w1f[nt][1], acc, 0, 0, 0);
                acc = __builtin_amdgcn_mfma_f32_16x16x32_bf16(afr[2], w1f[nt][2], acc, 0, 0, 0);
                acc = __builtin_amdgcn_mfma_f32_16x16x32_bf16(afr[3], w1f[nt][3], acc, 0, 0, 0);
                float hv0 = acc[0] + t1v[nt]; hv0 = hv0 > 0.f ? hv0 : hv0*0.01f;
                float hv1 = acc[1] + t1v[nt]; hv1 = hv1 > 0.f ? hv1 : hv1*0.01f;
                float hv2 = acc[2] + t1v[nt]; hv2 = hv2 > 0.f ? hv2 : hv2*0.01f;
                float hv3 = acc[3] + t1v[nt]; hv3 = hv3 > 0.f ? hv3 : hv3*0.01f;
                float ov0 = __shfl_xor(hv0, 1);
                float ov1 = __shfl_xor(hv1, 1);
                float ov2 = __shfl_xor(hv2, 1);
                float ov3 = __shfl_xor(hv3, 1);
                bool odd = (l15 & 1);
                float lo0 = odd ? ov2 : hv0,  hi0 = odd ? hv2 : ov0;
                float lo1 = odd ? ov3 : hv1,  hi1 = odd ? hv3 : ov1;
                int col = g*32 + nt*8 + (l15 >> 1);
                int row = h*32 + ms*16 + q*4 + (odd ? 2 : 0);
                sH1[row*68 + col]     = pk_trunc(lo0, hi0);
                sH1[(row+1)*68 + col] = pk_trunc(lo1, hi1);
            }
        }
        __syncthreads();
        #pragma unroll
        for (int sx = 0; sx < 2; ++sx) {
            short8 hfr[4];
            #pragma unroll
            for (int kt = 0; kt < 4; ++kt)
                hfr[kt] = *(const short8*)&sH1[(h*32 + sx*16 + l15)*68 + kt*16 + q*4];
            float part[4] = {0.f, 0.f, 0.f, 0.f};
            #pragma unroll
            for (int nt = 0; nt < 2; ++nt) {
                f32x4 acc = {0.f, 0.f, 0.f, 0.f};
                acc = __builtin_amdgcn_mfma_f32_16x16x32_bf16(hfr[0], w2f[nt][0], acc, 0, 0, 0);
                acc = __builtin_amdgcn_mfma_f32_16x16x32_bf16(hfr[1], w2f[nt][1], acc, 0, 0, 0);
                acc = __builtin_amdgcn_mfma_f32_16x16x32_bf16(hfr[2], w2f[nt][2], acc, 0, 0, 0);
                acc = __builtin_amdgcn_mfma_f32_16x16x32_bf16(hfr[3], w2f[nt][3], acc, 0, 0, 0);
                #pragma unroll
                for (int r = 0; r < 4; ++r) {
                    float hv = acc[r] + t2v[nt];
                    hv = hv > 0.f ? hv : hv*0.01f;
                    part[r] = fmaf(hv, w3v[nt], part[r]);
                }
            }
            #pragma unroll
            for (int r = 0; r < 4; ++r) {
                part[r] += __shfl_xor(part[r], 1);
                part[r] += __shfl_xor(part[r], 2);
                part[r] += __shfl_xor(part[r], 4);
                part[r] += __shfl_xor(part[r], 8);
            }
            if (l15 == 0)
                #pragma unroll
                for (int r = 0; r < 4; ++r)
                    sPart[g][h*32 + sx*16 + q*4 + r] = part[r];
        }
        __syncthreads();
        if (t < 64) {
            float logit = sPart[0][t] + sPart[1][t] + b3v;
            float sg = 1.f / (1.f + __expf(-logit));
            int i = i0 + ch*2 + (t >> 5);
            int j = j0 + (t & 31);
            float epl = (i == j) ? 0.f : ep[((size_t)(b*NPTS + i))*NPTS + j];
            ep_out[((size_t)(b*NPTS + i))*NPTS + j] = sg * epl;
        }
    }
}

__global__ __launch_bounds__(512)
void topk_norm_kernel(const float* __restrict__ ep_gen, float* __restrict__ ep_io) {
    __shared__ __align__(16) float r[NPTS];
    __shared__ float red[8];
    const int row = blockIdx.x;
    const int i   = row & (NPTS - 1);
    const int t   = threadIdx.x;
    const float* gen = &ep_gen[(size_t)row * NPTS];
    float* io        = &ep_io [(size_t)row * NPTS];
    float v = io[t];
    r[t] = v;
    float gv = (t == i) ? 0.f : gen[t];
    __syncthreads();
    float s_last = block_reduce_sum512(gv, red);
    int c = 0;
    #pragma unroll 4
    for (int k = 0; k < NPTS; k += 4) {
        float4 rv = *(const float4*)&r[k];
        c += (rv.x > v) + (rv.y > v) + (rv.z > v) + (rv.w > v);
    }
    float m = (c < KVAL) ? v : 0.f;
    float l1 = block_reduce_sum512(m, red);
    float scale = s_last / fmaxf(l1, 1e-12f);
    float f = m*scale + ((t == i) ? 1.f : 0.f) + 1e-6f;
    float s2 = block_reduce_sum512(f, red);
    io[t] = f / s2;
}

extern "C" void kernel_launch(void* const* d_in, const int* in_sizes, int n_in,
                              void* d_out, int out_size, void* d_ws, size_t ws_size,
                              hipStream_t stream) {
    const float* vp  = (const float*)d_in[0];
    const float* ep  = (const float*)d_in[1];
    const float* W1  = (const float*)d_in[2];
    const float* g1  = (const float*)d_in[3];
    const float* be1 = (const float*)d_in[4];
    const float* m1  = (const float*)d_in[5];
    const float* v1  = (const float*)d_in[6];
    const float* W2  = (const float*)d_in[7];
    const float* g2  = (const float*)d_in[8];
    const float* be2 = (const float*)d_in[9];
    const float* m2  = (const float*)d_in[10];
    const float* v2  = (const float*)d_in[11];
    const float* W3  = (const float*)d_in[12];
    const float* b3  = (const float*)d_in[13];

    float* out    = (float*)d_out;
    float* ep_out = out;                          // [2,512,512]
    float* ns_out = out + (size_t)NB*NPTS*NPTS;   // [2,512,512]

    const size_t need = 49152 + (size_t)NB*NPTS*NPTS*sizeof(float);  // 48K frags + 2M sg
    if (ws_size >= need) {
        uint4* wsp    = (uint4*)d_ws;
        float* sg_buf = (float*)((char*)d_ws + 49152);
        prep_weights<<<dim3(12), dim3(256), 0, stream>>>(W1, g1, v1, W2, g2, v2, wsp);
        mlp_tri_kernel<<<dim3(544, NB), dim3(256), 0, stream>>>(
            vp, wsp, g1, be1, m1, v1, g2, be2, m2, v2, W3, b3, ns_out, sg_buf);
        finish_kernel<<<dim3(NB*NPTS), dim3(512), 0, stream>>>(ep, sg_buf, ep_out, ns_out);
    } else {
        mlp_full_kernel<<<dim3(1024, NB), dim3(256), 0, stream>>>(
            vp, ep, W1, g1, be1, m1, v1, W2, g2, be2, m2, v2, W3, b3, ep_out, ns_out);
        topk_norm_kernel<<<dim3(NB*NPTS), dim3(512), 0, stream>>>(ep, ep_out);
    }
}